// Round 2
// baseline (2854.427 us; speedup 1.0000x reference)
//
#include <hip/hip_runtime.h>

#define EPS_ 1e-5f

typedef float f32x4 __attribute__((ext_vector_type(4)));
typedef short s16x8 __attribute__((ext_vector_type(8)));

static __device__ __forceinline__ short f2bf(float f) {
    unsigned u = __float_as_uint(f);
    unsigned r = (u + 0x7FFFu + ((u >> 16) & 1u)) >> 16;
    return (short)r;
}
static __device__ __forceinline__ float bf2f(short s) {
    return __uint_as_float(((unsigned)(unsigned short)s) << 16);
}

// ---------------------------------------------------------------------------
// Kernel 1: per-(b,t) QKV projection + PReLU + LN(chan,freq), write bf16.
// Q,K: [hb=h*2+b][t][o*64+f] (256); V row-major: [hb][t][ov*64+f] (1024)
// ---------------------------------------------------------------------------
__global__ __launch_bounds__(256) void qkv_kernel(
    const float* __restrict__ x,
    const float* __restrict__ Wq, const float* __restrict__ bq, const float* __restrict__ aq,
    const float* __restrict__ gq, const float* __restrict__ betq,
    const float* __restrict__ Wk, const float* __restrict__ bk, const float* __restrict__ ak,
    const float* __restrict__ gk, const float* __restrict__ betk,
    const float* __restrict__ Wv, const float* __restrict__ bv, const float* __restrict__ av,
    const float* __restrict__ gv, const float* __restrict__ betv,
    short* __restrict__ Qo, short* __restrict__ Ko, short* __restrict__ Vo)
{
    const int bt = blockIdx.x;
    const int b = bt >> 11, t = bt & 2047;
    const int tid = threadIdx.x;
    const int f = tid & 63;
    const int qtr = tid >> 6;           // 0..3 (also wave id)
    const int lane = tid & 63;

    __shared__ __align__(16) float ws[96 * 64];
    __shared__ float zs[96 * 64];
    __shared__ float stats[12][2];

    // stage weights: rows 0-15 Wq, 16-31 Wk, 32-95 Wv (each row = 64 in-chans)
#pragma unroll
    for (int k2 = 0; k2 < 6; ++k2) {
        int i4 = tid + k2 * 256;
        f32x4 v;
        if (i4 < 256)      v = ((const f32x4*)Wq)[i4];
        else if (i4 < 512) v = ((const f32x4*)Wk)[i4 - 256];
        else               v = ((const f32x4*)Wv)[i4 - 512];
        *(f32x4*)&ws[i4 * 4] = v;
    }
    __syncthreads();

    // x[b, :, t, f] into registers (64 chans)
    float xr[64];
#pragma unroll
    for (int c = 0; c < 64; ++c)
        xr[c] = x[(((size_t)b * 64 + c) * 2048 + t) * 64 + f];

    // 24 output rows per thread: row = qtr + 4*j
    float acc[24];
#pragma unroll
    for (int j = 0; j < 24; ++j) {
        int row = qtr + 4 * j;
        float a = 0.f;
#pragma unroll
        for (int c4 = 0; c4 < 16; ++c4) {
            f32x4 w = *(f32x4*)&ws[row * 64 + c4 * 4];
            a += w[0] * xr[c4 * 4] + w[1] * xr[c4 * 4 + 1] +
                 w[2] * xr[c4 * 4 + 2] + w[3] * xr[c4 * 4 + 3];
        }
        acc[j] = a;
    }

    // bias + PReLU, stash in LDS for LN stats
#pragma unroll
    for (int j = 0; j < 24; ++j) {
        int row = qtr + 4 * j;
        float bias, ap;
        if (row < 16)      { bias = bq[row];      ap = aq[row >> 2]; }
        else if (row < 32) { bias = bk[row - 16]; ap = ak[(row - 16) >> 2]; }
        else               { bias = bv[row - 32]; ap = av[(row - 32) >> 4]; }
        float z = acc[j] + bias;
        z = z >= 0.f ? z : ap * z;
        acc[j] = z;
        zs[row * 64 + f] = z;
    }
    __syncthreads();

    // 12 LN groups: 0-3 Q heads (4 rows x 64f), 4-7 K heads, 8-11 V heads (16 rows x 64f)
#pragma unroll
    for (int gi = 0; gi < 3; ++gi) {
        int grp = qtr * 3 + gi;
        int base_row, n;
        if (grp < 4)      { base_row = grp * 4;            n = 256; }
        else if (grp < 8) { base_row = 16 + (grp - 4) * 4; n = 256; }
        else              { base_row = 32 + (grp - 8) * 16; n = 1024; }
        int cnt = n >> 6;
        float s = 0.f, ss = 0.f;
        for (int i = 0; i < cnt; ++i) {
            float v = zs[(base_row + i) * 64 + lane];
            s += v; ss += v * v;
        }
#pragma unroll
        for (int msk = 32; msk >= 1; msk >>= 1) {
            s  += __shfl_xor(s, msk);
            ss += __shfl_xor(ss, msk);
        }
        if (lane == 0) {
            float mean = s / n;
            float var = ss / n - mean * mean;
            stats[grp][0] = mean;
            stats[grp][1] = rsqrtf(var + EPS_);
        }
    }
    __syncthreads();

    // normalize + gamma/beta + write bf16
#pragma unroll
    for (int j = 0; j < 24; ++j) {
        int row = qtr + 4 * j;
        if (row < 16) {
            int grp = row >> 2;
            float val = (acc[j] - stats[grp][0]) * stats[grp][1];
            val = val * gq[row * 64 + f] + betq[row * 64 + f];
            int h = row >> 2, o = row & 3;
            Qo[(((size_t)(h * 2 + b)) * 2048 + t) * 256 + o * 64 + f] = f2bf(val);
        } else if (row < 32) {
            int rr = row - 16, grp = 4 + (rr >> 2);
            float val = (acc[j] - stats[grp][0]) * stats[grp][1];
            val = val * gk[rr * 64 + f] + betk[rr * 64 + f];
            int h = rr >> 2, o = rr & 3;
            Ko[(((size_t)(h * 2 + b)) * 2048 + t) * 256 + o * 64 + f] = f2bf(val);
        } else {
            int rr = row - 32, grp = 8 + (rr >> 4);
            float val = (acc[j] - stats[grp][0]) * stats[grp][1];
            val = val * gv[rr * 64 + f] + betv[rr * 64 + f];
            int h = rr >> 4, ov = rr & 15;
            Vo[(((size_t)(h * 2 + b)) * 2048 + t) * 1024 + ov * 64 + f] = f2bf(val);
        }
    }
}

// ---------------------------------------------------------------------------
// Kernel 2: V row-major [hb][t][d] -> V^T [hb][d][t]  (64x64 bf16 tiles)
// ---------------------------------------------------------------------------
__global__ __launch_bounds__(256) void vtrans_kernel(
    const short* __restrict__ Vrm, short* __restrict__ Vt)
{
    const int t0 = blockIdx.x * 64;
    const int d0 = blockIdx.y * 64;
    const int hb = blockIdx.z;
    const int tid = threadIdx.x;
    __shared__ __align__(16) short tile[64 * 72];

#pragma unroll
    for (int k = 0; k < 2; ++k) {
        int q = tid + 256 * k;
        int row = q >> 3, slot = q & 7;
        s16x8 v = *(const s16x8*)(Vrm + ((size_t)hb * 2048 + t0 + row) * 1024 + d0 + slot * 8);
        *(s16x8*)&tile[row * 72 + slot * 8] = v;
    }
    __syncthreads();
#pragma unroll
    for (int k = 0; k < 2; ++k) {
        int q = tid + 256 * k;
        int drow = q >> 3, tslot = q & 7;
        s16x8 v;
#pragma unroll
        for (int i = 0; i < 8; ++i)
            v[i] = tile[(tslot * 8 + i) * 72 + drow];
        *(s16x8*)(Vt + ((size_t)hb * 1024 + d0 + drow) * 2048 + t0 + tslot * 8) = v;
    }
}

// ---------------------------------------------------------------------------
// Kernel 3: flash attention. 8 hb x 32 q-tiles (QBLK=64), 512 thr (8 waves).
// wave = (wr 0..3: 16 q-rows, wc 0..1: 512 v-cols). KBLK=64.
// Output O: bf16 in out-proj layout [b][h*16+ov][t][f].
// ---------------------------------------------------------------------------
__global__ __launch_bounds__(512, 2) void attn_kernel(
    const short* __restrict__ Qg, const short* __restrict__ Kg,
    const short* __restrict__ Vt, short* __restrict__ Ob)
{
    const int qt = blockIdx.x;     // 0..31
    const int hb = blockIdx.y;     // 0..7
    const int t0 = qt * 64;
    const int tid = threadIdx.x;
    const int lane = tid & 63;
    const int wid = tid >> 6;
    const int wr = wid >> 1, wc = wid & 1;
    const int g = lane >> 4, c16 = lane & 15;

    __shared__ __align__(16) short k_lds[64 * 256];      // 32 KB, XOR-swizzled 16B slots
    __shared__ __align__(16) short p_lds[64 * 72];       // 9 KB, padded
    __shared__ __align__(16) short v_lds[2][256 * 64];   // 2x32 KB, XOR-swizzled

    f32x4 oacc[4][8];
#pragma unroll
    for (int a = 0; a < 4; ++a)
#pragma unroll
        for (int bb = 0; bb < 8; ++bb)
#pragma unroll
            for (int r = 0; r < 4; ++r) oacc[a][bb][r] = 0.f;

    float m_r[4], l_r[4];
#pragma unroll
    for (int r = 0; r < 4; ++r) { m_r[r] = -1e30f; l_r[r] = 0.f; }

    const size_t qbase = ((size_t)hb * 2048 + t0 + wr * 16 + c16) * 256;

    for (int tile = 0; tile < 32; ++tile) {
        const int kt0 = tile * 64;

        // Q fragments for this wave's 16-row stripe (L1-hot reload each tile)
        s16x8 qf[8];
#pragma unroll
        for (int kf = 0; kf < 8; ++kf)
            qf[kf] = *(const s16x8*)(Qg + qbase + kf * 32 + g * 8);

        // stage K tile (64 keys x 256 d) into LDS with 16B-slot XOR swizzle
#pragma unroll
        for (int j = 0; j < 4; ++j) {
            int q_ = tid + 512 * j;
            int row = q_ >> 5, slot = q_ & 31;
            s16x8 v = *(const s16x8*)(Kg + ((size_t)hb * 2048 + kt0 + row) * 256 + slot * 8);
            *(s16x8*)&k_lds[row * 256 + (slot ^ (row & 7)) * 8] = v;
        }
        __syncthreads();   // barrier A

        // S = Q K^T  (16 rows x 64 keys per wave; wc pair duplicates)
        f32x4 sf[4];
#pragma unroll
        for (int nf = 0; nf < 4; ++nf)
#pragma unroll
            for (int r = 0; r < 4; ++r) sf[nf][r] = 0.f;
#pragma unroll
        for (int kf = 0; kf < 8; ++kf) {
#pragma unroll
            for (int nf = 0; nf < 4; ++nf) {
                int row = nf * 16 + c16;
                int slot = (kf * 4 + g) ^ (row & 7);
                s16x8 kb = *(const s16x8*)&k_lds[row * 256 + slot * 8];
                sf[nf] = __builtin_amdgcn_mfma_f32_16x16x32_bf16(qf[kf], kb, sf[nf], 0, 0, 0);
            }
        }

        // online softmax (rows live as reg r: row = 4*g + r)
#pragma unroll
        for (int nf = 0; nf < 4; ++nf)
#pragma unroll
            for (int r = 0; r < 4; ++r) sf[nf][r] *= 0.0625f;   // 1/sqrt(256)

        float mt[4];
#pragma unroll
        for (int r = 0; r < 4; ++r)
            mt[r] = fmaxf(fmaxf(sf[0][r], sf[1][r]), fmaxf(sf[2][r], sf[3][r]));
#pragma unroll
        for (int msk = 1; msk <= 8; msk <<= 1)
#pragma unroll
            for (int r = 0; r < 4; ++r)
                mt[r] = fmaxf(mt[r], __shfl_xor(mt[r], msk));

        float alpha[4], rs[4];
#pragma unroll
        for (int r = 0; r < 4; ++r) {
            float mn = fmaxf(m_r[r], mt[r]);
            alpha[r] = __expf(m_r[r] - mn);
            m_r[r] = mn;
        }
#pragma unroll
        for (int nf = 0; nf < 4; ++nf)
#pragma unroll
            for (int r = 0; r < 4; ++r)
                sf[nf][r] = __expf(sf[nf][r] - m_r[r]);
#pragma unroll
        for (int r = 0; r < 4; ++r)
            rs[r] = sf[0][r] + sf[1][r] + sf[2][r] + sf[3][r];
#pragma unroll
        for (int msk = 1; msk <= 8; msk <<= 1)
#pragma unroll
            for (int r = 0; r < 4; ++r)
                rs[r] += __shfl_xor(rs[r], msk);
#pragma unroll
        for (int r = 0; r < 4; ++r)
            l_r[r] = l_r[r] * alpha[r] + rs[r];

        // rescale O accumulators
#pragma unroll
        for (int a = 0; a < 4; ++a)
#pragma unroll
            for (int bb = 0; bb < 8; ++bb)
#pragma unroll
                for (int r = 0; r < 4; ++r)
                    oacc[a][bb][r] *= alpha[r];

        // write P (only wc==0 of each duplicate pair)
        if (wc == 0) {
#pragma unroll
            for (int nf = 0; nf < 4; ++nf)
#pragma unroll
                for (int r = 0; r < 4; ++r)
                    p_lds[(wr * 16 + g * 4 + r) * 72 + nf * 16 + c16] = f2bf(sf[nf][r]);
        }

        // prefetch V chunk 0 into regs (V^T: [hb][d][t], 16B contiguous in t)
        s16x8 vst[4];
#pragma unroll
        for (int j = 0; j < 4; ++j) {
            int q_ = tid + 512 * j;
            int row = q_ >> 3, slot = q_ & 7;
            vst[j] = *(const s16x8*)(Vt + ((size_t)hb * 1024 + row) * 2048 + kt0 + slot * 8);
        }
        __syncthreads();   // barrier B: P visible

        // P fragments (A-operand for PV)
        s16x8 pa[2];
#pragma unroll
        for (int ks = 0; ks < 2; ++ks)
            pa[ks] = *(const s16x8*)&p_lds[(wr * 16 + c16) * 72 + ks * 32 + g * 8];

        // PV over 4 v-col chunks of 256 (double-buffered LDS, reg prefetch)
#pragma unroll
        for (int cch = 0; cch < 4; ++cch) {
            s16x8 vnx[4];
            if (cch < 3) {
#pragma unroll
                for (int j = 0; j < 4; ++j) {
                    int q_ = tid + 512 * j;
                    int row = q_ >> 3, slot = q_ & 7;
                    vnx[j] = *(const s16x8*)(Vt + ((size_t)hb * 1024 + (cch + 1) * 256 + row) * 2048 + kt0 + slot * 8);
                }
            }
#pragma unroll
            for (int j = 0; j < 4; ++j) {
                int q_ = tid + 512 * j;
                int row = q_ >> 3, slot = q_ & 7;
                *(s16x8*)&v_lds[cch & 1][row * 64 + (slot ^ (row & 7)) * 8] = vst[j];
            }
            __syncthreads();
#pragma unroll
            for (int nf = 0; nf < 8; ++nf) {
                int row = wc * 128 + nf * 16 + c16;
#pragma unroll
                for (int ks = 0; ks < 2; ++ks) {
                    int slot = (ks * 4 + g) ^ (row & 7);
                    s16x8 vb = *(const s16x8*)&v_lds[cch & 1][row * 64 + slot * 8];
                    oacc[cch][nf] = __builtin_amdgcn_mfma_f32_16x16x32_bf16(pa[ks], vb, oacc[cch][nf], 0, 0, 0);
                }
            }
            if (cch < 3) {
#pragma unroll
                for (int j = 0; j < 4; ++j) vst[j] = vnx[j];
            }
        }
    }

    // epilogue: O /= l, write bf16 in [b][h*16+ov][t][f] layout
    const int h = hb >> 1, b = hb & 1;
#pragma unroll
    for (int r = 0; r < 4; ++r) l_r[r] = 1.f / l_r[r];
#pragma unroll
    for (int a = 0; a < 4; ++a) {
#pragma unroll
        for (int bb = 0; bb < 8; ++bb) {
            int vcol = a * 256 + wc * 128 + bb * 16 + c16;
            int cout = h * 16 + (vcol >> 6), ff = vcol & 63;
#pragma unroll
            for (int r = 0; r < 4; ++r) {
                int trow = t0 + wr * 16 + g * 4 + r;
                Ob[(((size_t)b * 64 + cout) * 2048 + trow) * 64 + ff] =
                    f2bf(oacc[a][bb][r] * l_r[r]);
            }
        }
    }
}

// ---------------------------------------------------------------------------
// Kernel 4: output projection + PReLU + LN(C,F) + residual
// ---------------------------------------------------------------------------
__global__ __launch_bounds__(256) void oproj_kernel(
    const short* __restrict__ Ob, const float* __restrict__ x,
    const float* __restrict__ Wp, const float* __restrict__ bp, const float* __restrict__ ap,
    const float* __restrict__ gp, const float* __restrict__ betp,
    float* __restrict__ out)
{
    const int bt = blockIdx.x;
    const int b = bt >> 11, t = bt & 2047;
    const int tid = threadIdx.x;
    const int f = tid & 63;
    const int qtr = tid >> 6;
    const int lane = tid & 63;

    __shared__ __align__(16) float wp[64 * 64];
    __shared__ float red[4][2];

#pragma unroll
    for (int k2 = 0; k2 < 4; ++k2) {
        int i4 = tid + k2 * 256;
        *(f32x4*)&wp[i4 * 4] = ((const f32x4*)Wp)[i4];
    }
    __syncthreads();

    float orr[64];
#pragma unroll
    for (int c = 0; c < 64; ++c)
        orr[c] = bf2f(Ob[(((size_t)b * 64 + c) * 2048 + t) * 64 + f]);

    const float ap0 = ap[0];
    float acc[16];
    float s = 0.f, ss = 0.f;
#pragma unroll
    for (int j = 0; j < 16; ++j) {
        int row = qtr + 4 * j;
        float a = 0.f;
#pragma unroll
        for (int c4 = 0; c4 < 16; ++c4) {
            f32x4 w = *(f32x4*)&wp[row * 64 + c4 * 4];
            a += w[0] * orr[c4 * 4] + w[1] * orr[c4 * 4 + 1] +
                 w[2] * orr[c4 * 4 + 2] + w[3] * orr[c4 * 4 + 3];
        }
        a += bp[row];
        a = a >= 0.f ? a : ap0 * a;
        acc[j] = a;
        s += a; ss += a * a;
    }
#pragma unroll
    for (int msk = 32; msk >= 1; msk >>= 1) {
        s  += __shfl_xor(s, msk);
        ss += __shfl_xor(ss, msk);
    }
    if (lane == 0) { red[qtr][0] = s; red[qtr][1] = ss; }
    __syncthreads();
    float ts  = red[0][0] + red[1][0] + red[2][0] + red[3][0];
    float tss = red[0][1] + red[1][1] + red[2][1] + red[3][1];
    float mean = ts * (1.f / 4096.f);
    float rstd = rsqrtf(tss * (1.f / 4096.f) - mean * mean + EPS_);

#pragma unroll
    for (int j = 0; j < 16; ++j) {
        int row = qtr + 4 * j;
        size_t idx = (((size_t)b * 64 + row) * 2048 + t) * 64 + f;
        out[idx] = (acc[j] - mean) * rstd * gp[row * 64 + f] + betp[row * 64 + f] + x[idx];
    }
}

// ---------------------------------------------------------------------------
extern "C" void kernel_launch(void* const* d_in, const int* in_sizes, int n_in,
                              void* d_out, int out_size, void* d_ws, size_t ws_size,
                              hipStream_t stream)
{
    const float* x    = (const float*)d_in[0];
    const float* Wq   = (const float*)d_in[1];
    const float* bq   = (const float*)d_in[2];
    const float* aq   = (const float*)d_in[3];
    const float* gq   = (const float*)d_in[4];
    const float* betq = (const float*)d_in[5];
    const float* Wk   = (const float*)d_in[6];
    const float* bk   = (const float*)d_in[7];
    const float* ak   = (const float*)d_in[8];
    const float* gk   = (const float*)d_in[9];
    const float* betk = (const float*)d_in[10];
    const float* Wv   = (const float*)d_in[11];
    const float* bv   = (const float*)d_in[12];
    const float* av   = (const float*)d_in[13];
    const float* gv   = (const float*)d_in[14];
    const float* betv = (const float*)d_in[15];
    const float* Wp   = (const float*)d_in[16];
    const float* bp   = (const float*)d_in[17];
    const float* ap   = (const float*)d_in[18];
    const float* gp   = (const float*)d_in[19];
    const float* betp = (const float*)d_in[20];

    // workspace layout (bf16 elements): Q 4M, K 4M, Vrm 16M, Vt 16M, O 16M
    short* Qb  = (short*)d_ws;
    short* Kb  = Qb  + (size_t)8 * 2048 * 256;
    short* Vrm = Kb  + (size_t)8 * 2048 * 256;
    short* Vt  = Vrm + (size_t)8 * 2048 * 1024;
    short* Ob  = Vt  + (size_t)8 * 2048 * 1024;

    qkv_kernel<<<4096, 256, 0, stream>>>(x, Wq, bq, aq, gq, betq,
                                         Wk, bk, ak, gk, betk,
                                         Wv, bv, av, gv, betv, Qb, Kb, Vrm);
    vtrans_kernel<<<dim3(32, 16, 8), 256, 0, stream>>>(Vrm, Vt);
    attn_kernel<<<dim3(32, 8), 512, 0, stream>>>(Qb, Kb, Vt, Ob);
    oproj_kernel<<<4096, 256, 0, stream>>>(Ob, x, Wp, bp, ap, gp, betp, (float*)d_out);
}

// Round 3
// 364.645 us; speedup vs baseline: 7.8280x; 7.8280x over previous
//
#include <hip/hip_runtime.h>

#define EPS_ 1e-5f

typedef float f32x4 __attribute__((ext_vector_type(4)));
typedef short s16x8 __attribute__((ext_vector_type(8)));

static __device__ __forceinline__ short f2bf(float f) {
    unsigned u = __float_as_uint(f);
    unsigned r = (u + 0x7FFFu + ((u >> 16) & 1u)) >> 16;
    return (short)r;
}
static __device__ __forceinline__ float bf2f(short s) {
    return __uint_as_float(((unsigned)(unsigned short)s) << 16);
}

// ---------------------------------------------------------------------------
// Kernel 0: convert weight stacks to bf16 once.
// Wbf[96][64]: rows 0-15 Wq(h*4+o), 16-31 Wk, 32-95 Wv(h*16+ov). Wpbf[64][64].
// ---------------------------------------------------------------------------
__global__ __launch_bounds__(256) void prep_kernel(
    const float* __restrict__ Wq, const float* __restrict__ Wk,
    const float* __restrict__ Wv, const float* __restrict__ Wp,
    short* __restrict__ Wbf, short* __restrict__ Wpbf)
{
    int i = blockIdx.x * 256 + threadIdx.x;
    if (i < 6144) {
        float v = (i < 1024) ? Wq[i] : (i < 2048 ? Wk[i - 1024] : Wv[i - 2048]);
        Wbf[i] = f2bf(v);
    } else if (i < 6144 + 4096) {
        Wpbf[i - 6144] = f2bf(Wp[i - 6144]);
    }
}

// ---------------------------------------------------------------------------
// Kernel 1: QKV projection via MFMA + PReLU + LN(chan,freq), write bf16.
// One block per (b,t). 256 thr = 4 waves; wave wid owns f-tile [wid*16,+16).
// Q,K: [hb=h*2+b][t][o*64+f] (256); V row-major: [hb][t][ov*64+f] (1024)
// ---------------------------------------------------------------------------
__global__ __launch_bounds__(256) void qkv_kernel(
    const float* __restrict__ x, const short* __restrict__ Wbf,
    const float* __restrict__ bq, const float* __restrict__ aq,
    const float* __restrict__ gq, const float* __restrict__ betq,
    const float* __restrict__ bk, const float* __restrict__ ak,
    const float* __restrict__ gk, const float* __restrict__ betk,
    const float* __restrict__ bv, const float* __restrict__ av,
    const float* __restrict__ gv, const float* __restrict__ betv,
    short* __restrict__ Qo, short* __restrict__ Ko, short* __restrict__ Vo)
{
    const int t = blockIdx.x;
    const int b = blockIdx.y;
    const int tid = threadIdx.x;
    const int wid = tid >> 6, lane = tid & 63;
    const int g = lane >> 4, c16 = lane & 15;
    const int f_ = tid & 63, cg = tid >> 6;

    __shared__ __align__(16) short wlds[96 * 64];   // XOR-swizzled 16B slots
    __shared__ __align__(16) short xs[64 * 64];     // X^T: xs[f][c], swizzled
    __shared__ float zs[96 * 64];                   // post-prelu activations
    __shared__ float stats[12][2];
    __shared__ float bias_l[96], alpha_l[96];

    // stage weights (bf16, swizzled): 768 16B chunks
#pragma unroll
    for (int j = 0; j < 3; ++j) {
        int i8 = tid + 256 * j;
        int row = i8 >> 3, cb = i8 & 7;
        s16x8 v = *(const s16x8*)(Wbf + i8 * 8);
        *(s16x8*)&wlds[row * 64 + ((cb ^ (row & 7)) * 8)] = v;
    }
    // stage bias / prelu-alpha
    if (tid < 96) {
        int row = tid; float bias, al;
        if (row < 16)      { bias = bq[row];      al = aq[row >> 2]; }
        else if (row < 32) { bias = bk[row - 16]; al = ak[(row - 16) >> 2]; }
        else               { bias = bv[row - 32]; al = av[(row - 32) >> 4]; }
        bias_l[row] = bias; alpha_l[row] = al;
    }
    // stage x transposed: thread (f_, cg); 8 chans per iter, 2 iters
#pragma unroll
    for (int it = 0; it < 2; ++it) {
        int cb = cg + 4 * it, c0 = cb * 8;
        s16x8 v;
#pragma unroll
        for (int i = 0; i < 8; ++i)
            v[i] = f2bf(x[(((size_t)b * 64 + c0 + i) * 2048 + t) * 64 + f_]);
        *(s16x8*)&xs[f_ * 64 + ((cb ^ (f_ & 7)) * 8)] = v;
    }
    __syncthreads();

    // MFMA: D[96 rows][16 f] per wave. B-frags shared across row-tiles.
    const int f0 = wid * 16;
    s16x8 bfr[2];
#pragma unroll
    for (int kk = 0; kk < 2; ++kk)
        bfr[kk] = *(const s16x8*)&xs[(f0 + c16) * 64 + (((kk * 4 + g) ^ (c16 & 7)) * 8)];

    f32x4 acc[6];
#pragma unroll
    for (int rt = 0; rt < 6; ++rt) {
#pragma unroll
        for (int r = 0; r < 4; ++r) acc[rt][r] = 0.f;
#pragma unroll
        for (int kk = 0; kk < 2; ++kk) {
            s16x8 a = *(const s16x8*)&wlds[(rt * 16 + c16) * 64 + (((kk * 4 + g) ^ (c16 & 7)) * 8)];
            acc[rt] = __builtin_amdgcn_mfma_f32_16x16x32_bf16(a, bfr[kk], acc[rt], 0, 0, 0);
        }
    }

    // bias + PReLU -> zs
#pragma unroll
    for (int rt = 0; rt < 6; ++rt)
#pragma unroll
        for (int r = 0; r < 4; ++r) {
            int row = rt * 16 + g * 4 + r;
            float z = acc[rt][r] + bias_l[row];
            z = z >= 0.f ? z : alpha_l[row] * z;
            zs[row * 64 + f0 + c16] = z;
        }
    __syncthreads();

    // 12 LN groups: 0-3 Q heads (4x64), 4-7 K heads, 8-11 V heads (16x64)
#pragma unroll
    for (int gi = 0; gi < 3; ++gi) {
        int grp = wid * 3 + gi;
        int base_row, n;
        if (grp < 4)      { base_row = grp * 4;             n = 256; }
        else if (grp < 8) { base_row = 16 + (grp - 4) * 4;  n = 256; }
        else              { base_row = 32 + (grp - 8) * 16; n = 1024; }
        int cnt = n >> 6;
        float s = 0.f, ss = 0.f;
        for (int i = 0; i < cnt; ++i) {
            float v = zs[(base_row + i) * 64 + lane];
            s += v; ss += v * v;
        }
#pragma unroll
        for (int msk = 32; msk >= 1; msk >>= 1) {
            s  += __shfl_xor(s, msk);
            ss += __shfl_xor(ss, msk);
        }
        if (lane == 0) {
            float mean = s / n;
            float var = ss / n - mean * mean;
            stats[grp][0] = mean;
            stats[grp][1] = rsqrtf(var + EPS_);
        }
    }
    __syncthreads();

    // normalize + gamma/beta + write bf16
#pragma unroll
    for (int j = 0; j < 24; ++j) {
        int row = cg + 4 * j;
        float zv = zs[row * 64 + f_];
        if (row < 16) {
            int grp = row >> 2;
            float val = (zv - stats[grp][0]) * stats[grp][1];
            val = val * gq[row * 64 + f_] + betq[row * 64 + f_];
            int h = row >> 2, o = row & 3;
            Qo[(((size_t)(h * 2 + b)) * 2048 + t) * 256 + o * 64 + f_] = f2bf(val);
        } else if (row < 32) {
            int rr = row - 16, grp = 4 + (rr >> 2);
            float val = (zv - stats[grp][0]) * stats[grp][1];
            val = val * gk[rr * 64 + f_] + betk[rr * 64 + f_];
            int h = rr >> 2, o = rr & 3;
            Ko[(((size_t)(h * 2 + b)) * 2048 + t) * 256 + o * 64 + f_] = f2bf(val);
        } else {
            int rr = row - 32, grp = 8 + (rr >> 4);
            float val = (zv - stats[grp][0]) * stats[grp][1];
            val = val * gv[rr * 64 + f_] + betv[rr * 64 + f_];
            int h = rr >> 4, ov = rr & 15;
            Vo[(((size_t)(h * 2 + b)) * 2048 + t) * 1024 + ov * 64 + f_] = f2bf(val);
        }
    }
}

// ---------------------------------------------------------------------------
// Kernel 2: V row-major [hb][t][d] -> V^T [hb][d][t]  (64x64 bf16 tiles)
// ---------------------------------------------------------------------------
__global__ __launch_bounds__(256) void vtrans_kernel(
    const short* __restrict__ Vrm, short* __restrict__ Vt)
{
    const int t0 = blockIdx.x * 64;
    const int d0 = blockIdx.y * 64;
    const int hb = blockIdx.z;
    const int tid = threadIdx.x;
    __shared__ __align__(16) short tile[64 * 72];

#pragma unroll
    for (int k = 0; k < 2; ++k) {
        int q = tid + 256 * k;
        int row = q >> 3, slot = q & 7;
        s16x8 v = *(const s16x8*)(Vrm + ((size_t)hb * 2048 + t0 + row) * 1024 + d0 + slot * 8);
        *(s16x8*)&tile[row * 72 + slot * 8] = v;
    }
    __syncthreads();
#pragma unroll
    for (int k = 0; k < 2; ++k) {
        int q = tid + 256 * k;
        int drow = q >> 3, tslot = q & 7;
        s16x8 v;
#pragma unroll
        for (int i = 0; i < 8; ++i)
            v[i] = tile[(tslot * 8 + i) * 72 + drow];
        *(s16x8*)(Vt + ((size_t)hb * 1024 + d0 + drow) * 2048 + t0 + tslot * 8) = v;
    }
}

// ---------------------------------------------------------------------------
// Kernel 3: flash attention. 8 hb x 32 q-tiles (QBLK=64), 512 thr (8 waves).
// wave = (wr 0..3: 16 q-rows, wc 0..1: 512 v-cols). KBLK=64.
// Output O: bf16 in out-proj layout [b][h*16+ov][t][f].
// ---------------------------------------------------------------------------
__global__ __launch_bounds__(512, 2) void attn_kernel(
    const short* __restrict__ Qg, const short* __restrict__ Kg,
    const short* __restrict__ Vt, short* __restrict__ Ob)
{
    const int qt = blockIdx.x;     // 0..31
    const int hb = blockIdx.y;     // 0..7
    const int t0 = qt * 64;
    const int tid = threadIdx.x;
    const int lane = tid & 63;
    const int wid = tid >> 6;
    const int wr = wid >> 1, wc = wid & 1;
    const int g = lane >> 4, c16 = lane & 15;

    __shared__ __align__(16) short k_lds[64 * 256];      // 32 KB, XOR-swizzled 16B slots
    __shared__ __align__(16) short p_lds[64 * 72];       // 9 KB, padded
    __shared__ __align__(16) short v_lds[2][256 * 64];   // 2x32 KB, XOR-swizzled

    f32x4 oacc[4][8];
#pragma unroll
    for (int a = 0; a < 4; ++a)
#pragma unroll
        for (int bb = 0; bb < 8; ++bb)
#pragma unroll
            for (int r = 0; r < 4; ++r) oacc[a][bb][r] = 0.f;

    float m_r[4], l_r[4];
#pragma unroll
    for (int r = 0; r < 4; ++r) { m_r[r] = -1e30f; l_r[r] = 0.f; }

    const size_t qbase = ((size_t)hb * 2048 + t0 + wr * 16 + c16) * 256;

    for (int tile = 0; tile < 32; ++tile) {
        const int kt0 = tile * 64;

        // Q fragments for this wave's 16-row stripe (L1-hot reload each tile)
        s16x8 qf[8];
#pragma unroll
        for (int kf = 0; kf < 8; ++kf)
            qf[kf] = *(const s16x8*)(Qg + qbase + kf * 32 + g * 8);

        // stage K tile (64 keys x 256 d) into LDS with 16B-slot XOR swizzle
#pragma unroll
        for (int j = 0; j < 4; ++j) {
            int q_ = tid + 512 * j;
            int row = q_ >> 5, slot = q_ & 31;
            s16x8 v = *(const s16x8*)(Kg + ((size_t)hb * 2048 + kt0 + row) * 256 + slot * 8);
            *(s16x8*)&k_lds[row * 256 + (slot ^ (row & 7)) * 8] = v;
        }
        __syncthreads();   // barrier A

        // S = Q K^T  (16 rows x 64 keys per wave; wc pair duplicates)
        f32x4 sf[4];
#pragma unroll
        for (int nf = 0; nf < 4; ++nf)
#pragma unroll
            for (int r = 0; r < 4; ++r) sf[nf][r] = 0.f;
#pragma unroll
        for (int kf = 0; kf < 8; ++kf) {
#pragma unroll
            for (int nf = 0; nf < 4; ++nf) {
                int row = nf * 16 + c16;
                int slot = (kf * 4 + g) ^ (row & 7);
                s16x8 kb = *(const s16x8*)&k_lds[row * 256 + slot * 8];
                sf[nf] = __builtin_amdgcn_mfma_f32_16x16x32_bf16(qf[kf], kb, sf[nf], 0, 0, 0);
            }
        }

        // online softmax (rows live as reg r: row = 4*g + r)
#pragma unroll
        for (int nf = 0; nf < 4; ++nf)
#pragma unroll
            for (int r = 0; r < 4; ++r) sf[nf][r] *= 0.0625f;   // 1/sqrt(256)

        float mt[4];
#pragma unroll
        for (int r = 0; r < 4; ++r)
            mt[r] = fmaxf(fmaxf(sf[0][r], sf[1][r]), fmaxf(sf[2][r], sf[3][r]));
#pragma unroll
        for (int msk = 1; msk <= 8; msk <<= 1)
#pragma unroll
            for (int r = 0; r < 4; ++r)
                mt[r] = fmaxf(mt[r], __shfl_xor(mt[r], msk));

        float alpha[4], rs[4];
#pragma unroll
        for (int r = 0; r < 4; ++r) {
            float mn = fmaxf(m_r[r], mt[r]);
            alpha[r] = __expf(m_r[r] - mn);
            m_r[r] = mn;
        }
#pragma unroll
        for (int nf = 0; nf < 4; ++nf)
#pragma unroll
            for (int r = 0; r < 4; ++r)
                sf[nf][r] = __expf(sf[nf][r] - m_r[r]);
#pragma unroll
        for (int r = 0; r < 4; ++r)
            rs[r] = sf[0][r] + sf[1][r] + sf[2][r] + sf[3][r];
#pragma unroll
        for (int msk = 1; msk <= 8; msk <<= 1)
#pragma unroll
            for (int r = 0; r < 4; ++r)
                rs[r] += __shfl_xor(rs[r], msk);
#pragma unroll
        for (int r = 0; r < 4; ++r)
            l_r[r] = l_r[r] * alpha[r] + rs[r];

        // rescale O accumulators
#pragma unroll
        for (int a = 0; a < 4; ++a)
#pragma unroll
            for (int bb = 0; bb < 8; ++bb)
#pragma unroll
                for (int r = 0; r < 4; ++r)
                    oacc[a][bb][r] *= alpha[r];

        // write P (only wc==0 of each duplicate pair)
        if (wc == 0) {
#pragma unroll
            for (int nf = 0; nf < 4; ++nf)
#pragma unroll
                for (int r = 0; r < 4; ++r)
                    p_lds[(wr * 16 + g * 4 + r) * 72 + nf * 16 + c16] = f2bf(sf[nf][r]);
        }

        // prefetch V chunk 0 into regs (V^T: [hb][d][t], 16B contiguous in t)
        s16x8 vst[4];
#pragma unroll
        for (int j = 0; j < 4; ++j) {
            int q_ = tid + 512 * j;
            int row = q_ >> 3, slot = q_ & 7;
            vst[j] = *(const s16x8*)(Vt + ((size_t)hb * 1024 + row) * 2048 + kt0 + slot * 8);
        }
        __syncthreads();   // barrier B: P visible

        // P fragments (A-operand for PV)
        s16x8 pa[2];
#pragma unroll
        for (int ks = 0; ks < 2; ++ks)
            pa[ks] = *(const s16x8*)&p_lds[(wr * 16 + c16) * 72 + ks * 32 + g * 8];

        // PV over 4 v-col chunks of 256 (double-buffered LDS, reg prefetch)
#pragma unroll
        for (int cch = 0; cch < 4; ++cch) {
            s16x8 vnx[4];
            if (cch < 3) {
#pragma unroll
                for (int j = 0; j < 4; ++j) {
                    int q_ = tid + 512 * j;
                    int row = q_ >> 3, slot = q_ & 7;
                    vnx[j] = *(const s16x8*)(Vt + ((size_t)hb * 1024 + (cch + 1) * 256 + row) * 2048 + kt0 + slot * 8);
                }
            }
#pragma unroll
            for (int j = 0; j < 4; ++j) {
                int q_ = tid + 512 * j;
                int row = q_ >> 3, slot = q_ & 7;
                *(s16x8*)&v_lds[cch & 1][row * 64 + (slot ^ (row & 7)) * 8] = vst[j];
            }
            __syncthreads();
#pragma unroll
            for (int nf = 0; nf < 8; ++nf) {
                int row = wc * 128 + nf * 16 + c16;
#pragma unroll
                for (int ks = 0; ks < 2; ++ks) {
                    int slot = (ks * 4 + g) ^ (row & 7);
                    s16x8 vb = *(const s16x8*)&v_lds[cch & 1][row * 64 + slot * 8];
                    oacc[cch][nf] = __builtin_amdgcn_mfma_f32_16x16x32_bf16(pa[ks], vb, oacc[cch][nf], 0, 0, 0);
                }
            }
            if (cch < 3) {
#pragma unroll
                for (int j = 0; j < 4; ++j) vst[j] = vnx[j];
            }
        }
    }

    // epilogue: O /= l, write bf16 in [b][h*16+ov][t][f] layout
    const int h = hb >> 1, b = hb & 1;
#pragma unroll
    for (int r = 0; r < 4; ++r) l_r[r] = 1.f / l_r[r];
#pragma unroll
    for (int a = 0; a < 4; ++a) {
#pragma unroll
        for (int bb = 0; bb < 8; ++bb) {
            int vcol = a * 256 + wc * 128 + bb * 16 + c16;
            int cout = h * 16 + (vcol >> 6), ff = vcol & 63;
#pragma unroll
            for (int r = 0; r < 4; ++r) {
                int trow = t0 + wr * 16 + g * 4 + r;
                Ob[(((size_t)b * 64 + cout) * 2048 + trow) * 64 + ff] =
                    f2bf(oacc[a][bb][r] * l_r[r]);
            }
        }
    }
}

// ---------------------------------------------------------------------------
// Kernel 4: output projection via MFMA + PReLU + LN(C,F) + residual
// One block per (b,t). 256 thr = 4 waves; wave wid owns f-tile [wid*16,+16).
// ---------------------------------------------------------------------------
__global__ __launch_bounds__(256) void oproj_kernel(
    const short* __restrict__ Ob, const float* __restrict__ x,
    const short* __restrict__ Wpbf,
    const float* __restrict__ bp, const float* __restrict__ ap,
    const float* __restrict__ gp, const float* __restrict__ betp,
    float* __restrict__ out)
{
    const int t = blockIdx.x;
    const int b = blockIdx.y;
    const int tid = threadIdx.x;
    const int wid = tid >> 6, lane = tid & 63;
    const int g = lane >> 4, c16 = lane & 15;
    const int f_ = tid & 63, cg = tid >> 6;

    __shared__ __align__(16) short wp[64 * 64];     // swizzled
    __shared__ __align__(16) short os[64 * 64];     // O^T: os[f][c], swizzled
    __shared__ float zs[64 * 64];
    __shared__ float red[4][2];

    // stage Wp bf16 (swizzled): 512 16B chunks
#pragma unroll
    for (int j = 0; j < 2; ++j) {
        int i8 = tid + 256 * j;
        int row = i8 >> 3, cb = i8 & 7;
        s16x8 v = *(const s16x8*)(Wpbf + i8 * 8);
        *(s16x8*)&wp[row * 64 + ((cb ^ (row & 7)) * 8)] = v;
    }
    // stage O transposed: thread (f_, cg); 8 chans per iter, 2 iters
#pragma unroll
    for (int it = 0; it < 2; ++it) {
        int cb = cg + 4 * it, c0 = cb * 8;
        s16x8 v;
#pragma unroll
        for (int i = 0; i < 8; ++i)
            v[i] = Ob[(((size_t)b * 64 + c0 + i) * 2048 + t) * 64 + f_];
        *(s16x8*)&os[f_ * 64 + ((cb ^ (f_ & 7)) * 8)] = v;
    }
    __syncthreads();

    const int f0 = wid * 16;
    s16x8 bfr[2];
#pragma unroll
    for (int kk = 0; kk < 2; ++kk)
        bfr[kk] = *(const s16x8*)&os[(f0 + c16) * 64 + (((kk * 4 + g) ^ (c16 & 7)) * 8)];

    const float ap0 = ap[0];
    f32x4 acc[4];
#pragma unroll
    for (int rt = 0; rt < 4; ++rt) {
#pragma unroll
        for (int r = 0; r < 4; ++r) acc[rt][r] = 0.f;
#pragma unroll
        for (int kk = 0; kk < 2; ++kk) {
            s16x8 a = *(const s16x8*)&wp[(rt * 16 + c16) * 64 + (((kk * 4 + g) ^ (c16 & 7)) * 8)];
            acc[rt] = __builtin_amdgcn_mfma_f32_16x16x32_bf16(a, bfr[kk], acc[rt], 0, 0, 0);
        }
    }

    // bias + PReLU -> zs
#pragma unroll
    for (int rt = 0; rt < 4; ++rt)
#pragma unroll
        for (int r = 0; r < 4; ++r) {
            int row = rt * 16 + g * 4 + r;
            float z = acc[rt][r] + bp[row];
            z = z >= 0.f ? z : ap0 * z;
            zs[row * 64 + f0 + c16] = z;
        }
    __syncthreads();

    // LN over all (64 chan x 64 f): per-thread partial over 16 rows at f_
    float s = 0.f, ss = 0.f;
#pragma unroll
    for (int j = 0; j < 16; ++j) {
        float v = zs[(cg + 4 * j) * 64 + f_];
        s += v; ss += v * v;
    }
#pragma unroll
    for (int msk = 32; msk >= 1; msk >>= 1) {
        s  += __shfl_xor(s, msk);
        ss += __shfl_xor(ss, msk);
    }
    if (lane == 0) { red[wid][0] = s; red[wid][1] = ss; }
    __syncthreads();
    float ts  = red[0][0] + red[1][0] + red[2][0] + red[3][0];
    float tss = red[0][1] + red[1][1] + red[2][1] + red[3][1];
    float mean = ts * (1.f / 4096.f);
    float rstd = rsqrtf(tss * (1.f / 4096.f) - mean * mean + EPS_);

#pragma unroll
    for (int j = 0; j < 16; ++j) {
        int row = cg + 4 * j;
        size_t idx = (((size_t)b * 64 + row) * 2048 + t) * 64 + f_;
        out[idx] = (zs[row * 64 + f_] - mean) * rstd * gp[row * 64 + f_]
                 + betp[row * 64 + f_] + x[idx];
    }
}

// ---------------------------------------------------------------------------
extern "C" void kernel_launch(void* const* d_in, const int* in_sizes, int n_in,
                              void* d_out, int out_size, void* d_ws, size_t ws_size,
                              hipStream_t stream)
{
    const float* x    = (const float*)d_in[0];
    const float* Wq   = (const float*)d_in[1];
    const float* bq   = (const float*)d_in[2];
    const float* aq   = (const float*)d_in[3];
    const float* gq   = (const float*)d_in[4];
    const float* betq = (const float*)d_in[5];
    const float* Wk   = (const float*)d_in[6];
    const float* bk   = (const float*)d_in[7];
    const float* ak   = (const float*)d_in[8];
    const float* gk   = (const float*)d_in[9];
    const float* betk = (const float*)d_in[10];
    const float* Wv   = (const float*)d_in[11];
    const float* bv   = (const float*)d_in[12];
    const float* av   = (const float*)d_in[13];
    const float* gv   = (const float*)d_in[14];
    const float* betv = (const float*)d_in[15];
    const float* Wp   = (const float*)d_in[16];
    const float* bp   = (const float*)d_in[17];
    const float* ap   = (const float*)d_in[18];
    const float* gp   = (const float*)d_in[19];
    const float* betp = (const float*)d_in[20];

    // workspace (bf16 elems): Q 4M, K 4M, Vrm 16M, Vt 16M, O 16M, Wbf, Wpbf
    short* Qb   = (short*)d_ws;
    short* Kb   = Qb   + (size_t)8 * 2048 * 256;
    short* Vrm  = Kb   + (size_t)8 * 2048 * 256;
    short* Vt   = Vrm  + (size_t)8 * 2048 * 1024;
    short* Obuf = Vt   + (size_t)8 * 2048 * 1024;
    short* Wbf  = Obuf + (size_t)8 * 2048 * 1024;
    short* Wpbf = Wbf  + 96 * 64;

    prep_kernel<<<40, 256, 0, stream>>>(Wq, Wk, Wv, Wp, Wbf, Wpbf);
    qkv_kernel<<<dim3(2048, 2), 256, 0, stream>>>(x, Wbf,
        bq, aq, gq, betq, bk, ak, gk, betk, bv, av, gv, betv, Qb, Kb, Vrm);
    vtrans_kernel<<<dim3(32, 16, 8), 256, 0, stream>>>(Vrm, Vt);
    attn_kernel<<<dim3(32, 8), 512, 0, stream>>>(Qb, Kb, Vt, Obuf);
    oproj_kernel<<<dim3(2048, 2), 256, 0, stream>>>(Obuf, x, Wpbf,
        bp, ap, gp, betp, (float*)d_out);
}

// Round 4
// 287.253 us; speedup vs baseline: 9.9370x; 1.2694x over previous
//
#include <hip/hip_runtime.h>

#define EPS_ 1e-5f

typedef float f32x4 __attribute__((ext_vector_type(4)));
typedef short s16x8 __attribute__((ext_vector_type(8)));

static __device__ __forceinline__ short f2bf(float f) {
    unsigned u = __float_as_uint(f);
    unsigned r = (u + 0x7FFFu + ((u >> 16) & 1u)) >> 16;
    return (short)r;
}
static __device__ __forceinline__ float bf2f(short s) {
    return __uint_as_float(((unsigned)(unsigned short)s) << 16);
}

// ---------------------------------------------------------------------------
// Kernel 0: convert weight stacks to bf16 once.
// ---------------------------------------------------------------------------
__global__ __launch_bounds__(256) void prep_kernel(
    const float* __restrict__ Wq, const float* __restrict__ Wk,
    const float* __restrict__ Wv, const float* __restrict__ Wp,
    short* __restrict__ Wbf, short* __restrict__ Wpbf)
{
    int i = blockIdx.x * 256 + threadIdx.x;
    if (i < 6144) {
        float v = (i < 1024) ? Wq[i] : (i < 2048 ? Wk[i - 1024] : Wv[i - 2048]);
        Wbf[i] = f2bf(v);
    } else if (i < 6144 + 4096) {
        Wpbf[i - 6144] = f2bf(Wp[i - 6144]);
    }
}

// ---------------------------------------------------------------------------
// Kernel 1: QKV projection via MFMA + PReLU + LN(chan,freq), write bf16.
// ---------------------------------------------------------------------------
__global__ __launch_bounds__(256) void qkv_kernel(
    const float* __restrict__ x, const short* __restrict__ Wbf,
    const float* __restrict__ bq, const float* __restrict__ aq,
    const float* __restrict__ gq, const float* __restrict__ betq,
    const float* __restrict__ bk, const float* __restrict__ ak,
    const float* __restrict__ gk, const float* __restrict__ betk,
    const float* __restrict__ bv, const float* __restrict__ av,
    const float* __restrict__ gv, const float* __restrict__ betv,
    short* __restrict__ Qo, short* __restrict__ Ko, short* __restrict__ Vo)
{
    const int t = blockIdx.x;
    const int b = blockIdx.y;
    const int tid = threadIdx.x;
    const int wid = tid >> 6, lane = tid & 63;
    const int g = lane >> 4, c16 = lane & 15;
    const int f_ = tid & 63, cg = tid >> 6;

    __shared__ __align__(16) short wlds[96 * 64];
    __shared__ __align__(16) short xs[64 * 64];
    __shared__ float zs[96 * 64];
    __shared__ float stats[12][2];
    __shared__ float bias_l[96], alpha_l[96];

#pragma unroll
    for (int j = 0; j < 3; ++j) {
        int i8 = tid + 256 * j;
        int row = i8 >> 3, cb = i8 & 7;
        s16x8 v = *(const s16x8*)(Wbf + i8 * 8);
        *(s16x8*)&wlds[row * 64 + ((cb ^ (row & 7)) * 8)] = v;
    }
    if (tid < 96) {
        int row = tid; float bias, al;
        if (row < 16)      { bias = bq[row];      al = aq[row >> 2]; }
        else if (row < 32) { bias = bk[row - 16]; al = ak[(row - 16) >> 2]; }
        else               { bias = bv[row - 32]; al = av[(row - 32) >> 4]; }
        bias_l[row] = bias; alpha_l[row] = al;
    }
#pragma unroll
    for (int it = 0; it < 2; ++it) {
        int cb = cg + 4 * it, c0 = cb * 8;
        s16x8 v;
#pragma unroll
        for (int i = 0; i < 8; ++i)
            v[i] = f2bf(x[(((size_t)b * 64 + c0 + i) * 2048 + t) * 64 + f_]);
        *(s16x8*)&xs[f_ * 64 + ((cb ^ (f_ & 7)) * 8)] = v;
    }
    __syncthreads();

    const int f0 = wid * 16;
    s16x8 bfr[2];
#pragma unroll
    for (int kk = 0; kk < 2; ++kk)
        bfr[kk] = *(const s16x8*)&xs[(f0 + c16) * 64 + (((kk * 4 + g) ^ (c16 & 7)) * 8)];

    f32x4 acc[6];
#pragma unroll
    for (int rt = 0; rt < 6; ++rt) {
#pragma unroll
        for (int r = 0; r < 4; ++r) acc[rt][r] = 0.f;
#pragma unroll
        for (int kk = 0; kk < 2; ++kk) {
            s16x8 a = *(const s16x8*)&wlds[(rt * 16 + c16) * 64 + (((kk * 4 + g) ^ (c16 & 7)) * 8)];
            acc[rt] = __builtin_amdgcn_mfma_f32_16x16x32_bf16(a, bfr[kk], acc[rt], 0, 0, 0);
        }
    }

#pragma unroll
    for (int rt = 0; rt < 6; ++rt)
#pragma unroll
        for (int r = 0; r < 4; ++r) {
            int row = rt * 16 + g * 4 + r;
            float z = acc[rt][r] + bias_l[row];
            z = z >= 0.f ? z : alpha_l[row] * z;
            zs[row * 64 + f0 + c16] = z;
        }
    __syncthreads();

#pragma unroll
    for (int gi = 0; gi < 3; ++gi) {
        int grp = wid * 3 + gi;
        int base_row, n;
        if (grp < 4)      { base_row = grp * 4;             n = 256; }
        else if (grp < 8) { base_row = 16 + (grp - 4) * 4;  n = 256; }
        else              { base_row = 32 + (grp - 8) * 16; n = 1024; }
        int cnt = n >> 6;
        float s = 0.f, ss = 0.f;
        for (int i = 0; i < cnt; ++i) {
            float v = zs[(base_row + i) * 64 + lane];
            s += v; ss += v * v;
        }
#pragma unroll
        for (int msk = 32; msk >= 1; msk >>= 1) {
            s  += __shfl_xor(s, msk);
            ss += __shfl_xor(ss, msk);
        }
        if (lane == 0) {
            float mean = s / n;
            float var = ss / n - mean * mean;
            stats[grp][0] = mean;
            stats[grp][1] = rsqrtf(var + EPS_);
        }
    }
    __syncthreads();

#pragma unroll
    for (int j = 0; j < 24; ++j) {
        int row = cg + 4 * j;
        float zv = zs[row * 64 + f_];
        if (row < 16) {
            int grp = row >> 2;
            float val = (zv - stats[grp][0]) * stats[grp][1];
            val = val * gq[row * 64 + f_] + betq[row * 64 + f_];
            int h = row >> 2, o = row & 3;
            Qo[(((size_t)(h * 2 + b)) * 2048 + t) * 256 + o * 64 + f_] = f2bf(val);
        } else if (row < 32) {
            int rr = row - 16, grp = 4 + (rr >> 2);
            float val = (zv - stats[grp][0]) * stats[grp][1];
            val = val * gk[rr * 64 + f_] + betk[rr * 64 + f_];
            int h = rr >> 2, o = rr & 3;
            Ko[(((size_t)(h * 2 + b)) * 2048 + t) * 256 + o * 64 + f_] = f2bf(val);
        } else {
            int rr = row - 32, grp = 8 + (rr >> 4);
            float val = (zv - stats[grp][0]) * stats[grp][1];
            val = val * gv[rr * 64 + f_] + betv[rr * 64 + f_];
            int h = rr >> 4, ov = rr & 15;
            Vo[(((size_t)(h * 2 + b)) * 2048 + t) * 1024 + ov * 64 + f_] = f2bf(val);
        }
    }
}

// ---------------------------------------------------------------------------
// Kernel 2: V row-major [hb][t][d] -> V^T [hb][d][t]
// ---------------------------------------------------------------------------
__global__ __launch_bounds__(256) void vtrans_kernel(
    const short* __restrict__ Vrm, short* __restrict__ Vt)
{
    const int t0 = blockIdx.x * 64;
    const int d0 = blockIdx.y * 64;
    const int hb = blockIdx.z;
    const int tid = threadIdx.x;
    __shared__ __align__(16) short tile[64 * 72];

#pragma unroll
    for (int k = 0; k < 2; ++k) {
        int q = tid + 256 * k;
        int row = q >> 3, slot = q & 7;
        s16x8 v = *(const s16x8*)(Vrm + ((size_t)hb * 2048 + t0 + row) * 1024 + d0 + slot * 8);
        *(s16x8*)&tile[row * 72 + slot * 8] = v;
    }
    __syncthreads();
#pragma unroll
    for (int k = 0; k < 2; ++k) {
        int q = tid + 256 * k;
        int drow = q >> 3, tslot = q & 7;
        s16x8 v;
#pragma unroll
        for (int i = 0; i < 8; ++i)
            v[i] = tile[(tslot * 8 + i) * 72 + drow];
        *(s16x8*)(Vt + ((size_t)hb * 1024 + d0 + drow) * 2048 + t0 + tslot * 8) = v;
    }
}

// ---------------------------------------------------------------------------
// Kernel 3: flash attention (no-max softmax: Q,K are LN'd so |S*scale| <~ 6).
// Grid (hb, qt) -> XCD-affine: all 32 q-tiles of one hb land on one XCD's L2.
// 512 thr = 8 waves. QK^T: wave (qs = wid>>1, kp = wid&1) computes q-stripe
// qs (16 rows) x key-half kp (32 keys): no duplicated MFMA.
// PV: wave owns d-slice [wid*128, +128) for ALL 64 q rows: each V fragment
// loaded exactly once per block, direct global->reg (L2-resident), no LDS.
// K: LDS double-buffer, reg-staged async (load early, ds_write late).
// 2 barriers per tile.
// ---------------------------------------------------------------------------
__global__ __launch_bounds__(512, 2) void attn_kernel(
    const short* __restrict__ Qg, const short* __restrict__ Kg,
    const short* __restrict__ Vt, short* __restrict__ Ob)
{
    const int hb = blockIdx.x;     // fast dim -> XCD affinity (linear%8 == hb)
    const int qt = blockIdx.y;
    const int t0 = qt * 64;
    const int tid = threadIdx.x;
    const int lane = tid & 63;
    const int wid = tid >> 6;
    const int qs = wid >> 1;       // q-stripe (QK^T)
    const int kp = wid & 1;        // key-half (QK^T)
    const int g = lane >> 4, c16 = lane & 15;

    __shared__ __align__(16) short k_lds[2][64 * 256];   // 64 KB dbuf
    __shared__ __align__(16) short p_lds[64 * 72];       // 9 KB
    __shared__ float lpart[2][64];

    // Q fragments for stripe qs, hoisted out of the tile loop
    const size_t qbase = ((size_t)hb * 2048 + t0 + qs * 16 + c16) * 256;
    s16x8 qf[8];
#pragma unroll
    for (int kf = 0; kf < 8; ++kf)
        qf[kf] = *(const s16x8*)(Qg + qbase + kf * 32 + g * 8);

    f32x4 oacc[32];
#pragma unroll
    for (int i = 0; i < 32; ++i)
#pragma unroll
        for (int r = 0; r < 4; ++r) oacc[i][r] = 0.f;

    float l_r[4] = {0.f, 0.f, 0.f, 0.f};

    const int srow = tid >> 5, sslot = tid & 31;

    // prologue: stage K tile 0 (swizzled dest)
    {
        s16x8 kreg0[4];
#pragma unroll
        for (int j = 0; j < 4; ++j) {
            int row = srow + 16 * j;
            kreg0[j] = *(const s16x8*)(Kg + ((size_t)hb * 2048 + row) * 256 + sslot * 8);
        }
#pragma unroll
        for (int j = 0; j < 4; ++j) {
            int row = srow + 16 * j;
            *(s16x8*)&k_lds[0][row * 256 + ((sslot ^ (row & 7)) * 8)] = kreg0[j];
        }
    }
    __syncthreads();

    const int dsl = wid * 128;                 // this wave's V d-slice
    const size_t vrow0 = (size_t)hb * 1024 + dsl + c16;

    for (int tile = 0; tile < 32; ++tile) {
        const int cur = tile & 1;
        const int kt0 = tile * 64;

        // issue next K tile loads early (latency hides under QK^T + PV)
        s16x8 kreg[4];
        if (tile < 31) {
#pragma unroll
            for (int j = 0; j < 4; ++j) {
                int row = srow + 16 * j;
                kreg[j] = *(const s16x8*)(Kg + ((size_t)hb * 2048 + kt0 + 64 + row) * 256 + sslot * 8);
            }
        }

        // QK^T: 16 q x 32 keys per wave, K=256
        f32x4 sf[2];
#pragma unroll
        for (int nf = 0; nf < 2; ++nf)
#pragma unroll
            for (int r = 0; r < 4; ++r) sf[nf][r] = 0.f;
#pragma unroll
        for (int kf = 0; kf < 8; ++kf) {
#pragma unroll
            for (int nf = 0; nf < 2; ++nf) {
                int row = kp * 32 + nf * 16 + c16;
                s16x8 kb = *(const s16x8*)&k_lds[cur][row * 256 + (((kf * 4 + g) ^ (c16 & 7)) * 8)];
                sf[nf] = __builtin_amdgcn_mfma_f32_16x16x32_bf16(qf[kf], kb, sf[nf], 0, 0, 0);
            }
        }

        // exp (no max subtraction) + partial row sums over this key-half
        float rs[4] = {0.f, 0.f, 0.f, 0.f};
#pragma unroll
        for (int nf = 0; nf < 2; ++nf)
#pragma unroll
            for (int r = 0; r < 4; ++r) {
                float p = __expf(sf[nf][r] * 0.0625f);
                sf[nf][r] = p;
                rs[r] += p;
            }
#pragma unroll
        for (int msk = 1; msk <= 8; msk <<= 1)
#pragma unroll
            for (int r = 0; r < 4; ++r) rs[r] += __shfl_xor(rs[r], msk);
#pragma unroll
        for (int r = 0; r < 4; ++r) l_r[r] += rs[r];

        // write this wave's P half (bf16)
#pragma unroll
        for (int nf = 0; nf < 2; ++nf)
#pragma unroll
            for (int r = 0; r < 4; ++r)
                p_lds[(qs * 16 + g * 4 + r) * 72 + kp * 32 + nf * 16 + c16] = f2bf(sf[nf][r]);

        __syncthreads();   // barrier 1: P visible; k_lds[cur] reads done

        // P A-fragments for all 4 q-stripes
        s16x8 pa[4][2];
#pragma unroll
        for (int s4 = 0; s4 < 4; ++s4)
#pragma unroll
            for (int ks = 0; ks < 2; ++ks)
                pa[s4][ks] = *(const s16x8*)&p_lds[(s4 * 16 + c16) * 72 + ks * 32 + g * 8];

        // PV: 8 d-tiles x 4 stripes x 2 ks, V direct from global, ring-3 prefetch
        s16x8 vf[3][2];
#pragma unroll
        for (int dt = 0; dt < 2; ++dt)
#pragma unroll
            for (int ks = 0; ks < 2; ++ks)
                vf[dt][ks] = *(const s16x8*)(Vt + (vrow0 + dt * 16) * 2048 + kt0 + (ks * 4 + g) * 8);

#pragma unroll
        for (int dt = 0; dt < 8; ++dt) {
            if (dt < 6) {
#pragma unroll
                for (int ks = 0; ks < 2; ++ks)
                    vf[(dt + 2) % 3][ks] = *(const s16x8*)(Vt + (vrow0 + (dt + 2) * 16) * 2048 + kt0 + (ks * 4 + g) * 8);
            }
#pragma unroll
            for (int s4 = 0; s4 < 4; ++s4)
#pragma unroll
                for (int ks = 0; ks < 2; ++ks)
                    oacc[dt * 4 + s4] = __builtin_amdgcn_mfma_f32_16x16x32_bf16(
                        pa[s4][ks], vf[dt % 3][ks], oacc[dt * 4 + s4], 0, 0, 0);
        }

        // write next K tile into the other LDS buffer
        if (tile < 31) {
#pragma unroll
            for (int j = 0; j < 4; ++j) {
                int row = srow + 16 * j;
                *(s16x8*)&k_lds[cur ^ 1][row * 256 + ((sslot ^ (row & 7)) * 8)] = kreg[j];
            }
        }
        __syncthreads();   // barrier 2: next K staged; p_lds reads done
    }

    // combine softmax denominators across the two key-half waves
    if (c16 == 0) {
#pragma unroll
        for (int r = 0; r < 4; ++r)
            lpart[kp][qs * 16 + g * 4 + r] = l_r[r];
    }
    __syncthreads();

    float li[16];
#pragma unroll
    for (int s4 = 0; s4 < 4; ++s4)
#pragma unroll
        for (int r = 0; r < 4; ++r) {
            int row = s4 * 16 + g * 4 + r;
            li[s4 * 4 + r] = 1.f / (lpart[0][row] + lpart[1][row]);
        }

    // epilogue: O /= l, write bf16 in [b][h*16+ov][t][f] layout
    const int h = hb >> 1, b = hb & 1;
#pragma unroll
    for (int dt = 0; dt < 8; ++dt) {
        int vcol = dsl + dt * 16 + c16;
        int cout = h * 16 + (vcol >> 6), ff = vcol & 63;
#pragma unroll
        for (int s4 = 0; s4 < 4; ++s4)
#pragma unroll
            for (int r = 0; r < 4; ++r) {
                int trow = t0 + s4 * 16 + g * 4 + r;
                Ob[(((size_t)b * 64 + cout) * 2048 + trow) * 64 + ff] =
                    f2bf(oacc[dt * 4 + s4][r] * li[s4 * 4 + r]);
            }
    }
}

// ---------------------------------------------------------------------------
// Kernel 4: output projection via MFMA + PReLU + LN(C,F) + residual
// ---------------------------------------------------------------------------
__global__ __launch_bounds__(256) void oproj_kernel(
    const short* __restrict__ Ob, const float* __restrict__ x,
    const short* __restrict__ Wpbf,
    const float* __restrict__ bp, const float* __restrict__ ap,
    const float* __restrict__ gp, const float* __restrict__ betp,
    float* __restrict__ out)
{
    const int t = blockIdx.x;
    const int b = blockIdx.y;
    const int tid = threadIdx.x;
    const int wid = tid >> 6, lane = tid & 63;
    const int g = lane >> 4, c16 = lane & 15;
    const int f_ = tid & 63, cg = tid >> 6;

    __shared__ __align__(16) short wp[64 * 64];
    __shared__ __align__(16) short os[64 * 64];
    __shared__ float zs[64 * 64];
    __shared__ float red[4][2];

#pragma unroll
    for (int j = 0; j < 2; ++j) {
        int i8 = tid + 256 * j;
        int row = i8 >> 3, cb = i8 & 7;
        s16x8 v = *(const s16x8*)(Wpbf + i8 * 8);
        *(s16x8*)&wp[row * 64 + ((cb ^ (row & 7)) * 8)] = v;
    }
#pragma unroll
    for (int it = 0; it < 2; ++it) {
        int cb = cg + 4 * it, c0 = cb * 8;
        s16x8 v;
#pragma unroll
        for (int i = 0; i < 8; ++i)
            v[i] = Ob[(((size_t)b * 64 + c0 + i) * 2048 + t) * 64 + f_];
        *(s16x8*)&os[f_ * 64 + ((cb ^ (f_ & 7)) * 8)] = v;
    }
    __syncthreads();

    const int f0 = wid * 16;
    s16x8 bfr[2];
#pragma unroll
    for (int kk = 0; kk < 2; ++kk)
        bfr[kk] = *(const s16x8*)&os[(f0 + c16) * 64 + (((kk * 4 + g) ^ (c16 & 7)) * 8)];

    const float ap0 = ap[0];
    f32x4 acc[4];
#pragma unroll
    for (int rt = 0; rt < 4; ++rt) {
#pragma unroll
        for (int r = 0; r < 4; ++r) acc[rt][r] = 0.f;
#pragma unroll
        for (int kk = 0; kk < 2; ++kk) {
            s16x8 a = *(const s16x8*)&wp[(rt * 16 + c16) * 64 + (((kk * 4 + g) ^ (c16 & 7)) * 8)];
            acc[rt] = __builtin_amdgcn_mfma_f32_16x16x32_bf16(a, bfr[kk], acc[rt], 0, 0, 0);
        }
    }

#pragma unroll
    for (int rt = 0; rt < 4; ++rt)
#pragma unroll
        for (int r = 0; r < 4; ++r) {
            int row = rt * 16 + g * 4 + r;
            float z = acc[rt][r] + bp[row];
            z = z >= 0.f ? z : ap0 * z;
            zs[row * 64 + f0 + c16] = z;
        }
    __syncthreads();

    float s = 0.f, ss = 0.f;
#pragma unroll
    for (int j = 0; j < 16; ++j) {
        float v = zs[(cg + 4 * j) * 64 + f_];
        s += v; ss += v * v;
    }
#pragma unroll
    for (int msk = 32; msk >= 1; msk >>= 1) {
        s  += __shfl_xor(s, msk);
        ss += __shfl_xor(ss, msk);
    }
    if (lane == 0) { red[wid][0] = s; red[wid][1] = ss; }
    __syncthreads();
    float ts  = red[0][0] + red[1][0] + red[2][0] + red[3][0];
    float tss = red[0][1] + red[1][1] + red[2][1] + red[3][1];
    float mean = ts * (1.f / 4096.f);
    float rstd = rsqrtf(tss * (1.f / 4096.f) - mean * mean + EPS_);

#pragma unroll
    for (int j = 0; j < 16; ++j) {
        int row = cg + 4 * j;
        size_t idx = (((size_t)b * 64 + row) * 2048 + t) * 64 + f_;
        out[idx] = (zs[row * 64 + f_] - mean) * rstd * gp[row * 64 + f_]
                 + betp[row * 64 + f_] + x[idx];
    }
}

// ---------------------------------------------------------------------------
extern "C" void kernel_launch(void* const* d_in, const int* in_sizes, int n_in,
                              void* d_out, int out_size, void* d_ws, size_t ws_size,
                              hipStream_t stream)
{
    const float* x    = (const float*)d_in[0];
    const float* Wq   = (const float*)d_in[1];
    const float* bq   = (const float*)d_in[2];
    const float* aq   = (const float*)d_in[3];
    const float* gq   = (const float*)d_in[4];
    const float* betq = (const float*)d_in[5];
    const float* Wk   = (const float*)d_in[6];
    const float* bk   = (const float*)d_in[7];
    const float* ak   = (const float*)d_in[8];
    const float* gk   = (const float*)d_in[9];
    const float* betk = (const float*)d_in[10];
    const float* Wv   = (const float*)d_in[11];
    const float* bv   = (const float*)d_in[12];
    const float* av   = (const float*)d_in[13];
    const float* gv   = (const float*)d_in[14];
    const float* betv = (const float*)d_in[15];
    const float* Wp   = (const float*)d_in[16];
    const float* bp   = (const float*)d_in[17];
    const float* ap   = (const float*)d_in[18];
    const float* gp   = (const float*)d_in[19];
    const float* betp = (const float*)d_in[20];

    short* Qb   = (short*)d_ws;
    short* Kb   = Qb   + (size_t)8 * 2048 * 256;
    short* Vrm  = Kb   + (size_t)8 * 2048 * 256;
    short* Vt   = Vrm  + (size_t)8 * 2048 * 1024;
    short* Obuf = Vt   + (size_t)8 * 2048 * 1024;
    short* Wbf  = Obuf + (size_t)8 * 2048 * 1024;
    short* Wpbf = Wbf  + 96 * 64;

    prep_kernel<<<40, 256, 0, stream>>>(Wq, Wk, Wv, Wp, Wbf, Wpbf);
    qkv_kernel<<<dim3(2048, 2), 256, 0, stream>>>(x, Wbf,
        bq, aq, gq, betq, bk, ak, gk, betk, bv, av, gv, betv, Qb, Kb, Vrm);
    vtrans_kernel<<<dim3(32, 16, 8), 256, 0, stream>>>(Vrm, Vt);
    attn_kernel<<<dim3(8, 32), 512, 0, stream>>>(Qb, Kb, Vt, Obuf);
    oproj_kernel<<<dim3(2048, 2), 256, 0, stream>>>(Obuf, x, Wpbf,
        bp, ap, gp, betp, (float*)d_out);
}